// Round 11
// baseline (77.875 us; speedup 1.0000x reference)
//
#include <hip/hip_runtime.h>

#define NW 3
#define NF 48
#define NHOST 16
#define NLAT 10
#define GOUT 16
#define EDIM 19
#define PDIM 10

// const-buffer layout (floats)
#define CB_M    0     // 19x19  Wq^T Wk
#define CB_P    361   // 19x19  Wout Wv
#define CB_G    722   // 19     bq^T Wk
#define CB_H    741   // 19     Wq^T bk
#define CB_R    760   // 19     Wout bv + bout
#define CB_C0   779   // 1      bq.bk
#define CB_WAL  780   // 3      gatW @ gal
#define CB_WAR  783   // 3      gatW @ gar
#define CB_CBIG 800   // 176    folded head biases (g = host*11 + {diff,p0..p9})
#define CB_BF   976   // 11264 ushorts (5632 floats): B-frags of Wbig^T, bf16
#define CB_TOT  10240

typedef __attribute__((ext_vector_type(8))) short bf16x8;
typedef __attribute__((ext_vector_type(4))) float f32x4;

__device__ __forceinline__ float frcp(float x){ return __builtin_amdgcn_rcpf(x); }
__device__ __forceinline__ float fsig(float x){ return frcp(1.f + __expf(-x)); }
__device__ __forceinline__ float ftanh(float x){ return 1.f - 2.f*frcp(1.f + __expf(2.f*x)); }
__device__ __forceinline__ unsigned short f2bf(float x){
    union { float f; unsigned u; } v; v.f = x;
    unsigned r = v.u + 0x7FFFu + ((v.u >> 16) & 1u);
    return (unsigned short)(r >> 16);
}

// ---------------- K0: fold weights; grid-parallel ----------------
// work items: [0,786) MHA folds | [786,962) cbig | [962,12226) B-frags
__global__ __launch_bounds__(256) void k_const(
    const float* __restrict__ Win, const float* __restrict__ bin,
    const float* __restrict__ Wout, const float* __restrict__ bout,
    const float* __restrict__ gatW, const float* __restrict__ gal,
    const float* __restrict__ gar, const float* __restrict__ encW,
    const float* __restrict__ encb,
    const float* __restrict__ aW, const float* __restrict__ ab,
    const float* __restrict__ pW, const float* __restrict__ pb,
    float* __restrict__ cb)
{
    const int w = blockIdx.x*blockDim.x + threadIdx.x;
    if (w < 786) {
        const int idx = w;
        float acc = 0.f;
        if (idx < 361) {                       // M[i][j] = sum_e Wq[e][i] Wk[e][j]
            int i = idx/19, j = idx%19;
            for (int e = 0; e < EDIM; ++e) acc += Win[e*EDIM+i]*Win[(EDIM+e)*EDIM+j];
        } else if (idx < 722) {                // P[i][j] = sum_e Wout[i][e] Wv[e][j]
            int k = idx-361; int i = k/19, j = k%19;
            for (int e = 0; e < EDIM; ++e) acc += Wout[i*EDIM+e]*Win[(2*EDIM+e)*EDIM+j];
        } else if (idx < 741) {                // g[j] = sum_e bq[e] Wk[e][j]
            int j = idx-722;
            for (int e = 0; e < EDIM; ++e) acc += bin[e]*Win[(EDIM+e)*EDIM+j];
        } else if (idx < 760) {                // h[i] = sum_e Wq[e][i] bk[e]
            int i = idx-741;
            for (int e = 0; e < EDIM; ++e) acc += Win[e*EDIM+i]*bin[EDIM+e];
        } else if (idx < 779) {                // r[i] = Wout bv + bout
            int i = idx-760; acc = bout[i];
            for (int e = 0; e < EDIM; ++e) acc += Wout[i*EDIM+e]*bin[2*EDIM+e];
        } else if (idx == 779) {               // c0 = bq.bk
            for (int e = 0; e < EDIM; ++e) acc += bin[e]*bin[EDIM+e];
        } else {                               // Wal/War
            int c = idx-780; int cc = c%3; bool left = c<3;
            for (int f2 = 0; f2 < GOUT; ++f2)
                acc += gatW[cc*GOUT+f2]*(left ? gal[f2] : gar[f2]);
        }
        cb[idx] = acc;
    } else if (w < 962) {
        const int g = w - 786;
        int host = g / 11, jj = g % 11;
        float acc = (jj == 0) ? (ab[0] - ab[1]) : pb[jj-1];
        for (int l = 0; l < NLAT; ++l) {
            float coef = (jj == 0) ? (aW[l] - aW[NLAT+l]) : pW[(jj-1)*NLAT + l];
            acc += coef * encb[host*NLAT + l];
        }
        cb[CB_CBIG + g] = acc;
    } else if (w < 12226) {
        // B-frags of Wbig^T [K=64 x N=176] bf16, mfma_16x16x32 layout:
        //  u = ((half*11+n)*64 + lane)*8 + j ; k = half*32+(lane>>4)*8+j ; g = n*16+(lane&15)
        unsigned short* bf = (unsigned short*)(cb + CB_BF);
        const int u = w - 962;
        int j    = u & 7;
        int lane = (u >> 3) & 63;
        int tile = u >> 9;              // 0..21
        int half = tile / 11, n = tile % 11;
        int k = half*32 + ((lane >> 4) & 3)*8 + j;
        int g = n*16 + (lane & 15);
        float acc = 0.f;
        if (k < 57) {
            int host = g / 11, jj = g % 11;
            for (int l = 0; l < NLAT; ++l) {
                float coef = (jj == 0) ? (aW[l] - aW[NLAT+l]) : pW[(jj-1)*NLAT + l];
                acc += coef * encW[(host*NLAT + l)*57 + k];
            }
        }
        bf[u] = f2bf(acc);
    }
}

// ---------------- K1: per-(b,w) GRU-gi + GAT -> ws1[25 streams][B] ----------------
// R11 restructure: x staged in LDS (stride 49 -> free 2-way bank pattern) and
// the computation phased so the true live set stays ~70 floats (x[48] no
// longer register-resident; gi stored before the GAT softmax). Fixes the
// presumed scratch-thrash of the 115-float live set AND the 576B-stride
// global loads (now one coalesced-ish staging pass).
__global__ __launch_bounds__(256) void k_front(
    const float* __restrict__ t, const float* __restrict__ Wih, const float* __restrict__ bih,
    const float* __restrict__ gatW, const float* __restrict__ cb,
    float* __restrict__ ws1, int B)
{
    __shared__ float xs[256*49];               // 49 KB; 3 blocks/CU fits 160KB
    const int tid = threadIdx.x;
    const int b0  = blockIdx.x*256;
    const int w   = blockIdx.y;

    // stage: 3072 float4s; thread handles f4 #tid, #tid+256, ... (12 iters)
#pragma unroll
    for (int r = 0; r < 12; ++r) {
        const int f4 = r*256 + tid;
        const int bl = f4 / 12, jj = f4 % 12;
        if (b0 + bl < B) {
            float4 v = *reinterpret_cast<const float4*>(
                t + ((size_t)(b0+bl)*NW + w)*NF + jj*4);
            float* d = xs + bl*49 + jj*4;
            d[0]=v.x; d[1]=v.y; d[2]=v.z; d[3]=v.w;
        }
    }
    __syncthreads();

    const int b = b0 + tid;
    if (b >= B) return;
    const float* xr = xs + tid*49;

    const float Wal0=cb[CB_WAL],Wal1=cb[CB_WAL+1],Wal2=cb[CB_WAL+2];
    const float War0=cb[CB_WAR],War1=cb[CB_WAR+1],War2=cb[CB_WAR+2];

    // phase A: gi (9 acc) + el/er (32 acc), x in 12-float chunks (4 hosts)
    float gi[9];
#pragma unroll
    for (int r2 = 0; r2 < 9; ++r2) gi[r2] = bih[r2];
    float el[NHOST], er[NHOST];
#pragma unroll
    for (int c = 0; c < 4; ++c) {
        float xc[12];
#pragma unroll
        for (int k = 0; k < 12; ++k) xc[k] = xr[c*12 + k];
#pragma unroll
        for (int r2 = 0; r2 < 9; ++r2) {
            float a = 0.f;
#pragma unroll
            for (int k = 0; k < 12; ++k) a += xc[k]*Wih[r2*NF + c*12 + k];
            gi[r2] += a;
        }
#pragma unroll
        for (int u = 0; u < 4; ++u) {
            const int uu = c*4 + u;
            el[uu] = xc[u*3]*Wal0 + xc[u*3+1]*Wal1 + xc[u*3+2]*Wal2;
            er[uu] = xc[u*3]*War0 + xc[u*3+1]*War1 + xc[u*3+2]*War2;
        }
    }
    // store gi now -> gi dead during softmax
    float* o = ws1 + (size_t)w*25*B + b;
#pragma unroll
    for (int r2 = 0; r2 < 9; ++r2) o[(size_t)r2*B] = gi[r2];

    // phase B: beta (peak live: el16+er16+ee16+beta16 = 64)
    float beta[NHOST];
#pragma unroll
    for (int u = 0; u < NHOST; ++u) beta[u] = 0.f;
#pragma unroll
    for (int v = 0; v < NHOST; ++v) {
        float ee[NHOST]; float sum = 0.f;
#pragma unroll
        for (int u = 0; u < NHOST; ++u) {
            float s = er[v] + el[u];
            s = fmaxf(s, 0.2f*s);
            ee[u] = __expf(s); sum += ee[u];
        }
        float inv = frcp(sum);
#pragma unroll
        for (int u = 0; u < NHOST; ++u) beta[u] += ee[u]*inv;
    }
    // phase C: weighted sum, x re-read from LDS (only beta live)
    float g0=0.f, g1=0.f, g2=0.f;
#pragma unroll
    for (int u = 0; u < NHOST; ++u) {
        float bu = beta[u]*(1.f/16.f);
        g0 += bu*xr[u*3+0]; g1 += bu*xr[u*3+1]; g2 += bu*xr[u*3+2];
    }
#pragma unroll
    for (int f2 = 0; f2 < GOUT; ++f2)
        o[(size_t)(9+f2)*B] = g0*gatW[f2] + g1*gatW[GOUT+f2] + g2*gatW[2*GOUT+f2];
}

// ---------------- K2: per-b GRU chain + folded MHA -> ws2bf[B][64] bf16 ----------------
__global__ __attribute__((amdgpu_flat_work_group_size(256,256), amdgpu_waves_per_eu(1,1)))
void k_mid(const float* __restrict__ ws1, const float* __restrict__ h0,
           const float* __restrict__ Whh, const float* __restrict__ bhh,
           const float* __restrict__ cb, unsigned short* __restrict__ ws2bf, int B)
{
    const int b = blockIdx.x*blockDim.x + threadIdx.x;
    if (b >= B) return;

    float h[3] = { h0[b*3+0], h0[b*3+1], h0[b*3+2] };
    float cw[57];
#pragma unroll
    for (int w = 0; w < NW; ++w) {
        const float* i1 = ws1 + (size_t)w*25*B + b;
        float gi[9];
#pragma unroll
        for (int r = 0; r < 9; ++r) gi[r] = i1[(size_t)r*B];
        float gh[9];
#pragma unroll
        for (int r = 0; r < 9; ++r)
            gh[r] = bhh[r] + h[0]*Whh[r*3+0] + h[1]*Whh[r*3+1] + h[2]*Whh[r*3+2];
#pragma unroll
        for (int j = 0; j < 3; ++j) {
            float rg = fsig(gi[j]   + gh[j]);
            float zg = fsig(gi[3+j] + gh[3+j]);
            float ng = ftanh(gi[6+j] + rg*gh[6+j]);
            h[j] = (1.f - zg)*ng + zg*h[j];
        }
        cw[w*EDIM+0]=h[0]; cw[w*EDIM+1]=h[1]; cw[w*EDIM+2]=h[2];
#pragma unroll
        for (int f2 = 0; f2 < GOUT; ++f2) cw[w*EDIM+3+f2] = i1[(size_t)(9+f2)*B];
    }
    // scores_st = (cs.M.ct + g.ct + h.cs + c0)/sqrt(E)
    float hs[NW];
#pragma unroll
    for (int s = 0; s < NW; ++s) {
        float a = 0.f;
#pragma unroll
        for (int i = 0; i < EDIM; ++i) a += cw[s*EDIM+i]*cb[CB_H+i];
        hs[s] = a;
    }
    const float c0 = cb[CB_C0];
    float sc[NW][NW];
#pragma unroll
    for (int tt = 0; tt < NW; ++tt) {
        float mt[EDIM];
#pragma unroll
        for (int i = 0; i < EDIM; ++i) {
            float a = 0.f;
#pragma unroll
            for (int j = 0; j < EDIM; ++j) a += cb[CB_M+i*EDIM+j]*cw[tt*EDIM+j];
            mt[i] = a;
        }
        float gt = 0.f;
#pragma unroll
        for (int j = 0; j < EDIM; ++j) gt += cb[CB_G+j]*cw[tt*EDIM+j];
#pragma unroll
        for (int s = 0; s < NW; ++s) {
            float a = 0.f;
#pragma unroll
            for (int i = 0; i < EDIM; ++i) a += cw[s*EDIM+i]*mt[i];
            sc[s][tt] = (a + gt + hs[s] + c0) * 0.2294157338705618f;
        }
    }
    float attw[NW][NW];
#pragma unroll
    for (int s = 0; s < NW; ++s) {
        float m = fmaxf(sc[s][0], fmaxf(sc[s][1], sc[s][2]));
        float e0=__expf(sc[s][0]-m), e1=__expf(sc[s][1]-m), e2=__expf(sc[s][2]-m);
        float inv = frcp(e0+e1+e2);
        attw[s][0]=e0*inv; attw[s][1]=e1*inv; attw[s][2]=e2*inv;
    }
    // overwrite cw[tt] <- PC[tt] = P @ cw[tt]
#pragma unroll
    for (int tt = 0; tt < NW; ++tt) {
        float pc[EDIM];
#pragma unroll
        for (int i = 0; i < EDIM; ++i) {
            float a = 0.f;
#pragma unroll
            for (int j = 0; j < EDIM; ++j) a += cb[CB_P+i*EDIM+j]*cw[tt*EDIM+j];
            pc[i] = a;
        }
#pragma unroll
        for (int i = 0; i < EDIM; ++i) cw[tt*EDIM+i] = pc[i];
    }
    // emit 64 bf16 (57 outputs + 7 zero pad) as 8x 16B chunks, b-major layout
    unsigned short* ob = ws2bf + (size_t)b*64;
#pragma unroll
    for (int c = 0; c < 8; ++c) {
        union { uint4 q; unsigned short s[8]; } pk;
#pragma unroll
        for (int e = 0; e < 8; ++e) {
            const int idx = c*8 + e;          // compile-time constant
            float val = 0.f;
            if (idx < 57) {
                const int s2 = idx / EDIM, i = idx % EDIM;
                val = cb[CB_R+i] + attw[s2][0]*cw[i] + attw[s2][1]*cw[EDIM+i]
                    + attw[s2][2]*cw[2*EDIM+i];
            }
            pk.s[e] = f2bf(val);
        }
        *reinterpret_cast<uint4*>(ob + c*8) = pk.q;
    }
}

// ---------------- K3: encoder+heads GEMM via MFMA ----------------
__global__ __launch_bounds__(256) void k_enc(
    const unsigned short* __restrict__ ws2bf, const float* __restrict__ cb,
    float* __restrict__ outA, float* __restrict__ outP, int B)
{
    __shared__ float lg[64][178];              // 64 b's x 176 logits (+2 pad)
    const int lane = threadIdx.x & 63;
    const int wv   = __builtin_amdgcn_readfirstlane(threadIdx.x >> 6);
    const int b0   = blockIdx.x*64;
    if (b0 >= B) return;

    // A-frags: brow = b0 + wv*16 + (lane&15), k = half*32 + (lane>>4)*8 + j
    const int brow = b0 + wv*16 + (lane & 15);
    const int koff = (lane >> 4) * 8;
    const unsigned short* ap = ws2bf + (size_t)brow*64;
    union { uint4 q; bf16x8 v; } a0, a1;
    a0.q = *reinterpret_cast<const uint4*>(ap + koff);
    a1.q = *reinterpret_cast<const uint4*>(ap + 32 + koff);

    const uint4* bfq = (const uint4*)(cb + CB_BF);   // frag (tile) -> uint4 per lane
    const int r0 = wv*16 + ((lane >> 4) << 2);       // LDS row base for this lane's acc
#pragma unroll
    for (int n = 0; n < 11; ++n) {
        union { uint4 q; bf16x8 v; } bf0, bf1;
        bf0.q = bfq[(size_t)n*64 + lane];            // half 0
        bf1.q = bfq[(size_t)(11 + n)*64 + lane];     // half 1
        f32x4 acc = {0.f, 0.f, 0.f, 0.f};
        acc = __builtin_amdgcn_mfma_f32_16x16x32_bf16(a0.v, bf0.v, acc, 0, 0, 0);
        acc = __builtin_amdgcn_mfma_f32_16x16x32_bf16(a1.v, bf1.v, acc, 0, 0, 0);
        const int c = n*16 + (lane & 15);
#pragma unroll
        for (int r = 0; r < 4; ++r) lg[r0 + r][c] = acc[r];
    }
    __syncthreads();

    // heads: thread covers host=(tid&15), 4 b's
    const int host = threadIdx.x & 15;
    const int tg   = threadIdx.x >> 4;               // 0..15
    const float* cbig = cb + CB_CBIG;
#pragma unroll
    for (int i = 0; i < 4; ++i) {
        const int bl = tg + 16*i;
        const int b  = b0 + bl;
        float v[11];
#pragma unroll
        for (int jj = 0; jj < 11; ++jj)
            v[jj] = lg[bl][host*11 + jj] + cbig[host*11 + jj];
        float p0 = fsig(v[0]);
        float2 av; av.x = p0; av.y = 1.f - p0;
        *reinterpret_cast<float2*>(outA + (size_t)b*32 + host*2) = av;
        float* pP = outP + (size_t)b*160 + host*10;
#pragma unroll
        for (int p = 0; p < 5; ++p) {
            float2 pv; pv.x = fsig(v[1 + 2*p]); pv.y = fsig(v[2 + 2*p]);
            *reinterpret_cast<float2*>(pP + 2*p) = pv;
        }
    }
}

extern "C" void kernel_launch(void* const* d_in, const int* in_sizes, int n_in,
                              void* d_out, int out_size, void* d_ws, size_t ws_size,
                              hipStream_t stream) {
    const float* t    = (const float*)d_in[0];
    const float* h0   = (const float*)d_in[2];
    const float* Wih  = (const float*)d_in[3];
    const float* Whh  = (const float*)d_in[4];
    const float* bih  = (const float*)d_in[5];
    const float* bhh  = (const float*)d_in[6];
    const float* gatW = (const float*)d_in[7];
    const float* gal  = (const float*)d_in[8];
    const float* gar  = (const float*)d_in[9];
    const float* Win  = (const float*)d_in[10];
    const float* bin  = (const float*)d_in[11];
    const float* Wout = (const float*)d_in[12];
    const float* bout = (const float*)d_in[13];
    const float* encW = (const float*)d_in[14];
    const float* encb = (const float*)d_in[15];
    const float* aW   = (const float*)d_in[16];
    const float* ab   = (const float*)d_in[17];
    const float* pW   = (const float*)d_in[18];
    const float* pb   = (const float*)d_in[19];

    const int B = in_sizes[0] / (NW * NF);
    float* cb  = (float*)d_ws;
    float* ws1 = cb + CB_TOT;
    unsigned short* ws2bf = (unsigned short*)(ws1 + (size_t)25*NW*B);
    float* outA = (float*)d_out;
    float* outP = (float*)d_out + (size_t)B*32;

    k_const<<<dim3(48), 256, 0, stream>>>(Win, bin, Wout, bout, gatW, gal, gar,
                                          encW, encb, aW, ab, pW, pb, cb);
    k_front<<<dim3((B+255)/256, NW), 256, 0, stream>>>(t, Wih, bih, gatW, cb, ws1, B);
    k_mid<<<dim3((B+255)/256), 256, 0, stream>>>(ws1, h0, Whh, bhh, cb, ws2bf, B);
    k_enc<<<dim3((B+63)/64), 256, 0, stream>>>(ws2bf, cb, outA, outP, B);
}